// Round 7
// baseline (279.511 us; speedup 1.0000x reference)
//
#include <hip/hip_runtime.h>

constexpr int N_DST1 = 50000;
constexpr int N_DST2 = 10000;
constexpr int E1     = 2000000;
constexpr int E2     = 400000;
constexpr int IN_F   = 128;
constexpr int H_F    = 256;
constexpr int N_CLS  = 47;

// Workspace layout (bytes)
constexpr size_t RP1_OFF = 0;          // 50001 int
constexpr size_t RP2_OFF = 204800;     // 10001 int
constexpr size_t BPS_OFF = 245760;     // Ws1 packed bf16 frags: 64 KB
constexpr size_t BPN_OFF = 311296;     // Wn1 packed: 64 KB
constexpr size_t BP2_OFF = 376832;     // [Ws2;Wn2] packed: 48 KB
constexpr size_t X8_OFF  = 430080;     // x fp8: 200000*128 = 25.6 MB
constexpr size_t HN1_OFF = 26030080;   // hn1 bf16: 12.8 MB
constexpr size_t Y_OFF   = 38830080;   // y = relu(h)@Wn2, bf16 [50000][64]: 6.4 MB
constexpr size_t ZS_OFF  = 45230080;   // z = relu(h)@Ws2, f32 [10000][64]: 2.56 MB
// total ~47.8 MB

using f32x4  = __attribute__((ext_vector_type(4))) float;
using f32x2  = __attribute__((ext_vector_type(2))) float;
using short8 = __attribute__((ext_vector_type(8))) short;

__device__ __forceinline__ ushort f2bf(float f) {
    union { float f; unsigned u; } v; v.f = f;
    unsigned u = v.u;
    return (ushort)((u + 0x7fffu + ((u >> 16) & 1u)) >> 16);
}

__device__ __forceinline__ float bflo(unsigned x) {
    union { unsigned q; float f; } w; w.q = x << 16; return w.f;
}
__device__ __forceinline__ float bfhi(unsigned x) {
    union { unsigned q; float f; } w; w.q = x & 0xffff0000u; return w.f;
}

// ---- fused setup: cast x->fp8 | pack weights | rowptrs ----
constexpr int CAST_BLKS = 200000 * IN_F / 8 / 256;  // 12500
constexpr int PACK_BLKS = 44;
constexpr int RP_BLKS   = (N_DST1 + N_DST2 + 2 + 255) / 256;  // 236

__global__ __launch_bounds__(256) void setup_all(
    const float* __restrict__ x, unsigned char* __restrict__ x8,
    const float* __restrict__ Ws1, const float* __restrict__ Wn1,
    const float* __restrict__ Ws2, const float* __restrict__ Wn2,
    ushort* __restrict__ bps, ushort* __restrict__ bpn, ushort* __restrict__ bp2,
    const int* __restrict__ dst1, const int* __restrict__ dst2,
    int* __restrict__ rp1, int* __restrict__ rp2) {
    int b = blockIdx.x;
    if (b < CAST_BLKS) {
        int i = b * 256 + threadIdx.x;  // groups of 8 floats
        float4 v0 = ((const float4*)x)[2 * i];
        float4 v1 = ((const float4*)x)[2 * i + 1];
        int p0 = __builtin_amdgcn_cvt_pk_fp8_f32(v0.x, v0.y, 0, false);
        p0     = __builtin_amdgcn_cvt_pk_fp8_f32(v0.z, v0.w, p0, true);
        int p1 = __builtin_amdgcn_cvt_pk_fp8_f32(v1.x, v1.y, 0, false);
        p1     = __builtin_amdgcn_cvt_pk_fp8_f32(v1.z, v1.w, p1, true);
        uint2 o; o.x = (unsigned)p0; o.y = (unsigned)p1;
        ((uint2*)x8)[i] = o;
    } else if (b < CAST_BLKS + PACK_BLKS) {
        int pb = b - CAST_BLKS;
        if (pb < 32) {
            const float* W = (pb < 16) ? Ws1 : Wn1;
            ushort* P      = (pb < 16) ? bps : bpn;
            int idx = (pb & 15) * 256 + threadIdx.x;  // 0..4095
            int lane = idx & 63, kb = (idx >> 6) & 3, nb = idx >> 8;
            int n  = nb * 16 + (lane & 15);
            int k0 = kb * 32 + ((lane >> 4) * 8);
            ushort tmp[8];
#pragma unroll
            for (int j = 0; j < 8; ++j) tmp[j] = f2bf(W[(k0 + j) * H_F + n]);
            ((uint4*)P)[idx] = *(uint4*)tmp;
        } else {
            int idx = (pb - 32) * 256 + threadIdx.x;  // 0..3071
            if (idx < 3072) {
                int lane = idx & 63, rem = idx >> 6;
                int nb = rem % 3, kb = rem / 3;
                int col = nb * 16 + (lane & 15);
                int k0  = (kb & 7) * 32 + ((lane >> 4) * 8);
                const float* W = (kb < 8) ? Ws2 : Wn2;
                ushort tmp[8];
#pragma unroll
                for (int j = 0; j < 8; ++j)
                    tmp[j] = (col < N_CLS) ? f2bf(W[(k0 + j) * N_CLS + col]) : (ushort)0;
                ((uint4*)bp2)[(kb * 3 + nb) * 64 + lane] = *(uint4*)tmp;
            }
        }
    } else {
        int idx = (b - CAST_BLKS - PACK_BLKS) * 256 + threadIdx.x;
        const int* dst; int* rp; int E; int target;
        if (idx <= N_DST1) { dst = dst1; rp = rp1; E = E1; target = idx; }
        else if (idx <= N_DST1 + 1 + N_DST2) {
            dst = dst2; rp = rp2; E = E2; target = idx - (N_DST1 + 1);
        } else return;
        int lo = 0, hi = E;
        while (lo < hi) {
            int mid = (lo + hi) >> 1;
            if (dst[mid] < target) lo = mid + 1; else hi = mid;
        }
        rp[target] = lo;
    }
}

// ---- layer-1 mean agg: one wave/dst; idx preload + shfl distribute ----
// x8 row = 128 B = 8 uint4. lane t: edge-slot g=t>>3, chunk c=t&7 (16 B).
// NOTE: every __shfl executes with all 64 lanes active (shfl from an
// exec-masked lane is undefined on CDNA).
__global__ __launch_bounds__(256) void agg1b(const unsigned char* __restrict__ x8,
                                             const int* __restrict__ src,
                                             const int* __restrict__ rp,
                                             ushort* __restrict__ hn) {
    int t = threadIdx.x & 63;
    int d = blockIdx.x * 4 + (threadIdx.x >> 6);
    int s = rp[d], e = rp[d + 1];
    int deg = e - s;
    const uint4* x4 = (const uint4*)x8;  // row stride 8 uint4
    int g = t >> 3, c = t & 7;
    f32x2 a2[8] = {};
    auto accv = [&](uint4 v) {
        a2[0] += __builtin_amdgcn_cvt_pk_f32_fp8((int)v.x, false);
        a2[1] += __builtin_amdgcn_cvt_pk_f32_fp8((int)v.x, true);
        a2[2] += __builtin_amdgcn_cvt_pk_f32_fp8((int)v.y, false);
        a2[3] += __builtin_amdgcn_cvt_pk_f32_fp8((int)v.y, true);
        a2[4] += __builtin_amdgcn_cvt_pk_f32_fp8((int)v.z, false);
        a2[5] += __builtin_amdgcn_cvt_pk_f32_fp8((int)v.z, true);
        a2[6] += __builtin_amdgcn_cvt_pk_f32_fp8((int)v.w, false);
        a2[7] += __builtin_amdgcn_cvt_pk_f32_fp8((int)v.w, true);
    };
    for (int b0 = s; b0 < e; b0 += 64) {
        int nb = min(64, e - b0);
        int idx = 0;
        if (t < nb) idx = src[b0 + t];  // coalesced
        int nfull = nb >> 3;
        int j = 0;
        for (; j + 4 <= nfull; j += 4) {
            int e0 = __shfl(idx, (j + 0) * 8 + g);
            int e1 = __shfl(idx, (j + 1) * 8 + g);
            int e2 = __shfl(idx, (j + 2) * 8 + g);
            int e3 = __shfl(idx, (j + 3) * 8 + g);
            uint4 v0 = x4[(size_t)e0 * 8 + c];
            uint4 v1 = x4[(size_t)e1 * 8 + c];
            uint4 v2 = x4[(size_t)e2 * 8 + c];
            uint4 v3 = x4[(size_t)e3 * 8 + c];
            accv(v0); accv(v1); accv(v2); accv(v3);
        }
        for (; j < nfull; ++j) {
            int e0 = __shfl(idx, j * 8 + g);
            uint4 v = x4[(size_t)e0 * 8 + c];
            accv(v);
        }
        int rem = nb & 7;
        int er = __shfl(idx, (nfull * 8 + g) & 63);  // all lanes active here
        if (g < rem) {
            uint4 v = x4[(size_t)er * 8 + c];
            accv(v);
        }
    }
    // reduce over edge-slots g (lanes xor 8,16,32)
#pragma unroll
    for (int q = 0; q < 8; ++q) {
#pragma unroll
        for (int h = 0; h < 2; ++h) {
            float av = a2[q][h];
            av += __shfl_xor(av, 8);
            av += __shfl_xor(av, 16);
            av += __shfl_xor(av, 32);
            a2[q][h] = av;
        }
    }
    if (t < 8) {  // lane c==t owns features t*16..t*16+15
        float inv = 1.f / fmaxf((float)deg, 1.f);
        unsigned o[8];
#pragma unroll
        for (int p = 0; p < 8; ++p)
            o[p] = (unsigned)f2bf(a2[p][0] * inv) |
                   ((unsigned)f2bf(a2[p][1] * inv) << 16);
        uint4* hrow = (uint4*)hn + (size_t)d * 16 + t * 2;  // row = 16 uint4
        hrow[0] = make_uint4(o[0], o[1], o[2], o[3]);
        hrow[1] = make_uint4(o[4], o[5], o[6], o[7]);
    }
}

// ---- layer 1 GEMM + fused y/z projections ----
// Phase 1 (barrier-free): wave w computes h tile cols [w*64, w*64+64),
// stages relu(h) bf16 tile to LDS.
// Phase 2: y = relu(h)@Wn2 (all blocks) and z = relu(h)@Ws2 (blocks with
// m0 < N_DST2, i.e. the first 625). K=256 split 4 ways, LDS reduce,
// wave 0 writes y rows (bf16, 47 data + pad) and z rows (f32).
__global__ __launch_bounds__(256) void gemm1_mfma(
    const float* __restrict__ x, const ushort* __restrict__ hn1,
    const ushort* __restrict__ BpS, const ushort* __restrict__ BpN,
    const ushort* __restrict__ P2, const float* __restrict__ b1,
    ushort* __restrict__ y, float* __restrict__ z) {
    __shared__ ushort lh[16][264];          // relu(h) tile, 2-way-free stride
    __shared__ f32x4 pred[3][6][64];        // waves 1..3 partials: [q]=y, [3+q]=z
    int tid = threadIdx.x;
    int wave = tid >> 6, lane = tid & 63;
    int m0 = blockIdx.x * 16;            // 3125 * 16 = 50000 exactly
    int nb0 = wave * 4;                  // 4 nb blocks of 16 cols each
    int mloc = lane & 15;
    int mrow = m0 + mloc;
    int koff = (lane >> 4) * 8;
    bool zb = (m0 < N_DST2);             // block-uniform

    // hoisted A fragments: ph0 = x (fp32->bf16), ph1 = hn1 (bf16)
    const float*  Af = x   + (size_t)mrow * IN_F;
    const ushort* Ah = hn1 + (size_t)mrow * IN_F;
    short8 a0[4], a1[4];
#pragma unroll
    for (int kb = 0; kb < 4; ++kb) {
        float4 q0 = *(const float4*)(Af + kb * 32 + koff);
        float4 q1 = *(const float4*)(Af + kb * 32 + koff + 4);
        a0[kb][0] = (short)f2bf(q0.x); a0[kb][1] = (short)f2bf(q0.y);
        a0[kb][2] = (short)f2bf(q0.z); a0[kb][3] = (short)f2bf(q0.w);
        a0[kb][4] = (short)f2bf(q1.x); a0[kb][5] = (short)f2bf(q1.y);
        a0[kb][6] = (short)f2bf(q1.z); a0[kb][7] = (short)f2bf(q1.w);
        a1[kb] = *(const short8*)(Ah + kb * 32 + koff);
    }

    f32x4 acc[4];
#pragma unroll
    for (int nb = 0; nb < 4; ++nb) acc[nb] = (f32x4){0.f, 0.f, 0.f, 0.f};

#pragma unroll
    for (int kb = 0; kb < 4; ++kb)
#pragma unroll
        for (int nb = 0; nb < 4; ++nb) {
            short8 b = *(const short8*)(BpS + ((size_t)((nb0 + nb) * 4 + kb) * 64 + lane) * 8);
            acc[nb] = __builtin_amdgcn_mfma_f32_16x16x32_bf16(a0[kb], b, acc[nb], 0, 0, 0);
        }
#pragma unroll
    for (int kb = 0; kb < 4; ++kb)
#pragma unroll
        for (int nb = 0; nb < 4; ++nb) {
            short8 b = *(const short8*)(BpN + ((size_t)((nb0 + nb) * 4 + kb) * 64 + lane) * 8);
            acc[nb] = __builtin_amdgcn_mfma_f32_16x16x32_bf16(a1[kb], b, acc[nb], 0, 0, 0);
        }

    int crow0 = (lane >> 4) * 4;         // local row base
    int ccol  = lane & 15;
#pragma unroll
    for (int nb = 0; nb < 4; ++nb) {
        size_t col = (size_t)(nb0 + nb) * 16 + ccol;
        float bias = b1[col];
#pragma unroll
        for (int r = 0; r < 4; ++r) {
            int row = crow0 + r;
            float v = fmaxf(acc[nb][r] + bias, 0.f);
            lh[row][col] = f2bf(v);
        }
    }
    __syncthreads();

    // ---- phase 2: y (+z) projections, wave w handles k in [w*64, w*64+64) ----
    f32x4 accY[3], accZ[3];
#pragma unroll
    for (int q = 0; q < 3; ++q) {
        accY[q] = (f32x4){0.f, 0.f, 0.f, 0.f};
        accZ[q] = (f32x4){0.f, 0.f, 0.f, 0.f};
    }
#pragma unroll
    for (int i = 0; i < 2; ++i) {
        int kb = wave * 2 + i;           // local k0 = kb*32
        short8 a = *(const short8*)&lh[mloc][kb * 32 + koff];
#pragma unroll
        for (int q = 0; q < 3; ++q) {
            short8 bn = *(const short8*)(P2 + ((size_t)((8 + kb) * 3 + q) * 64 + lane) * 8);
            accY[q] = __builtin_amdgcn_mfma_f32_16x16x32_bf16(a, bn, accY[q], 0, 0, 0);
        }
        if (zb) {
#pragma unroll
            for (int q = 0; q < 3; ++q) {
                short8 bs = *(const short8*)(P2 + ((size_t)(kb * 3 + q) * 64 + lane) * 8);
                accZ[q] = __builtin_amdgcn_mfma_f32_16x16x32_bf16(a, bs, accZ[q], 0, 0, 0);
            }
        }
    }
    if (wave != 0) {
#pragma unroll
        for (int q = 0; q < 3; ++q) pred[wave - 1][q][lane] = accY[q];
        if (zb) {
#pragma unroll
            for (int q = 0; q < 3; ++q) pred[wave - 1][3 + q][lane] = accZ[q];
        }
    }
    __syncthreads();
    if (wave == 0) {
#pragma unroll
        for (int q = 0; q < 3; ++q) {
            f32x4 v = accY[q];
            v += pred[0][q][lane]; v += pred[1][q][lane]; v += pred[2][q][lane];
#pragma unroll
            for (int r = 0; r < 4; ++r)
                y[(size_t)(m0 + crow0 + r) * 64 + q * 16 + ccol] = f2bf(v[r]);
        }
#pragma unroll
        for (int r = 0; r < 4; ++r)      // zero pad cols 48..63
            y[(size_t)(m0 + crow0 + r) * 64 + 48 + ccol] = 0;
        if (zb) {
#pragma unroll
            for (int q = 0; q < 3; ++q) {
                f32x4 v = accZ[q];
                v += pred[0][3 + q][lane]; v += pred[1][3 + q][lane];
                v += pred[2][3 + q][lane];
#pragma unroll
                for (int r = 0; r < 4; ++r)
                    z[(size_t)(m0 + crow0 + r) * 64 + q * 16 + ccol] = v[r];
            }
        }
    }
}

// ---- layer-2 mean agg over y rows (128 B bf16) + final output ----
// One wave/dst; idx preload + shfl distribute; epilogue adds the
// precomputed self projection z and bias, writes out directly.
__global__ __launch_bounds__(256) void agg2y(const ushort* __restrict__ y,
                                             const int* __restrict__ src,
                                             const int* __restrict__ rp,
                                             const float* __restrict__ z,
                                             const float* __restrict__ b2,
                                             float* __restrict__ out) {
    int t = threadIdx.x & 63;
    int d = blockIdx.x * 4 + (threadIdx.x >> 6);
    int s = rp[d], e = rp[d + 1];
    int deg = e - s;
    const uint4* y4 = (const uint4*)y;  // row stride 8 uint4 (128 B)
    int g = t >> 3, c = t & 7;
    float a[8] = {};
    auto accv = [&](uint4 v) {
        a[0] += bflo(v.x); a[1] += bfhi(v.x);
        a[2] += bflo(v.y); a[3] += bfhi(v.y);
        a[4] += bflo(v.z); a[5] += bfhi(v.z);
        a[6] += bflo(v.w); a[7] += bfhi(v.w);
    };
    for (int b0 = s; b0 < e; b0 += 64) {
        int nb = min(64, e - b0);
        int idx = 0;
        if (t < nb) idx = src[b0 + t];  // coalesced
        int nfull = nb >> 3;
        int j = 0;
        for (; j + 4 <= nfull; j += 4) {
            int e0 = __shfl(idx, (j + 0) * 8 + g);
            int e1 = __shfl(idx, (j + 1) * 8 + g);
            int e2 = __shfl(idx, (j + 2) * 8 + g);
            int e3 = __shfl(idx, (j + 3) * 8 + g);
            uint4 v0 = y4[(size_t)e0 * 8 + c];
            uint4 v1 = y4[(size_t)e1 * 8 + c];
            uint4 v2 = y4[(size_t)e2 * 8 + c];
            uint4 v3 = y4[(size_t)e3 * 8 + c];
            accv(v0); accv(v1); accv(v2); accv(v3);
        }
        for (; j < nfull; ++j) {
            int e0 = __shfl(idx, j * 8 + g);
            uint4 v = y4[(size_t)e0 * 8 + c];
            accv(v);
        }
        int rem = nb & 7;
        int er = __shfl(idx, (nfull * 8 + g) & 63);  // all lanes active here
        if (g < rem) {
            uint4 v = y4[(size_t)er * 8 + c];
            accv(v);
        }
    }
    // reduce over edge-slots g (lanes xor 8,16,32)
#pragma unroll
    for (int q = 0; q < 8; ++q) {
        float av = a[q];
        av += __shfl_xor(av, 8);
        av += __shfl_xor(av, 16);
        av += __shfl_xor(av, 32);
        a[q] = av;
    }
    if (t < 8) {  // lane t owns y cols t*8..t*8+7
        float inv = 1.f / fmaxf((float)deg, 1.f);
        const float* zr = z + (size_t)d * 64 + t * 8;
#pragma unroll
        for (int p = 0; p < 8; ++p) {
            int col = t * 8 + p;
            if (col < N_CLS)
                out[(size_t)d * N_CLS + col] = a[p] * inv + zr[p] + b2[col];
        }
    }
}

extern "C" void kernel_launch(void* const* d_in, const int* in_sizes, int n_in,
                              void* d_out, int out_size, void* d_ws, size_t ws_size,
                              hipStream_t stream) {
    const float* x   = (const float*)d_in[0];
    const float* Ws1 = (const float*)d_in[1];
    const float* Wn1 = (const float*)d_in[2];
    const float* b1  = (const float*)d_in[3];
    const float* Ws2 = (const float*)d_in[4];
    const float* Wn2 = (const float*)d_in[5];
    const float* b2  = (const float*)d_in[6];
    const int* src1  = (const int*)d_in[7];
    const int* dst1  = (const int*)d_in[8];
    const int* src2  = (const int*)d_in[9];
    const int* dst2  = (const int*)d_in[10];
    float* out = (float*)d_out;

    char* ws = (char*)d_ws;
    int*           rp1 = (int*)(ws + RP1_OFF);
    int*           rp2 = (int*)(ws + RP2_OFF);
    ushort*        bps = (ushort*)(ws + BPS_OFF);
    ushort*        bpn = (ushort*)(ws + BPN_OFF);
    ushort*        bp2 = (ushort*)(ws + BP2_OFF);
    unsigned char* x8  = (unsigned char*)(ws + X8_OFF);
    ushort*        hn1 = (ushort*)(ws + HN1_OFF);
    ushort*        y   = (ushort*)(ws + Y_OFF);
    float*         z   = (float*)(ws + ZS_OFF);

    setup_all<<<CAST_BLKS + PACK_BLKS + RP_BLKS, 256, 0, stream>>>(
        x, x8, Ws1, Wn1, Ws2, Wn2, bps, bpn, bp2, dst1, dst2, rp1, rp2);
    agg1b<<<N_DST1 / 4, 256, 0, stream>>>(x8, src1, rp1, hn1);
    gemm1_mfma<<<N_DST1 / 16, 256, 0, stream>>>(x, hn1, bps, bpn, bp2, b1, y, z);
    agg2y<<<N_DST2 / 4, 256, 0, stream>>>(y, src2, rp2, z, b2, out);
}